// Round 1
// 461.847 us; speedup vs baseline: 1.1349x; 1.1349x over previous
//
#include <hip/hip_runtime.h>
#include <hip/hip_bf16.h>
#include <stdint.h>

#define ALPHA 0.01f

typedef __attribute__((ext_vector_type(8))) short short8;
typedef __attribute__((ext_vector_type(4))) float f32x4;
typedef __attribute__((ext_vector_type(4))) float float4_;
typedef __attribute__((ext_vector_type(4))) unsigned short ushort4_;
typedef unsigned int u32;

// round-to-nearest-even f32 -> bf16 bit pattern
static __device__ __forceinline__ unsigned short f2bf(float f) {
    union { float f; u32 u; } v; v.f = f;
    u32 r = v.u + 0x7FFF + ((v.u >> 16) & 1);
    return (unsigned short)(r >> 16);
}

// async global->LDS, 16B per lane. LDS dest must be wave-uniform base + lane*16.
static __device__ __forceinline__ void lds_load16(const void* g, void* l) {
    __builtin_amdgcn_global_load_lds((const __attribute__((address_space(1))) u32*)g,
                                     (__attribute__((address_space(3))) u32*)l, 16, 0, 0);
}

// ---------------------------------------------------------------------------
// Kernel 1: cast W1,W2 to bf16 transposed (WT[n][k] = W[k][n])
__global__ __launch_bounds__(256) void k_prep_w(const float* __restrict__ W1, const float* __restrict__ W2,
                                                unsigned short* __restrict__ W1T, unsigned short* __restrict__ W2T) {
    int bb = blockIdx.x;
    const float* W = (bb & 256) ? W2 : W1;
    unsigned short* WT = (bb & 256) ? W2T : W1T;
    int n = bb & 255, k = threadIdx.x;
    WT[n * 256 + k] = f2bf(W[k * 256 + n]);
}

// Kernel 2: u[v][d] = sum_n W[d][n]*a_half[n]
__global__ __launch_bounds__(256) void k_prep_u(const float* __restrict__ W1, const float* __restrict__ a1,
                                                const float* __restrict__ W2, const float* __restrict__ a2,
                                                float* __restrict__ u) {
    int v = blockIdx.x;
    const float* W = (v < 2) ? W1 : W2;
    const float* a = ((v < 2) ? a1 : a2) + (v & 1) * 256;
    int d = threadIdx.x;
    float acc = 0.f;
    for (int n = 0; n < 256; n++) acc += W[d * 256 + n] * a[n];
    u[v * 256 + d] = acc;
}

// Kernel 3: cast inputs to bf16 + compute the 4 score GEMVs in fp32.
__global__ __launch_bounds__(256) void k_cast_s(const float* __restrict__ in1, const float* __restrict__ in2,
                                                const float* __restrict__ u,
                                                unsigned short* __restrict__ in1b, unsigned short* __restrict__ in2b,
                                                float* __restrict__ s) {
    int gid = blockIdx.x * 4 + (threadIdx.x >> 6);   // one wave per row
    int tensor = gid >> 14;
    int row = gid & 16383;
    int lane = threadIdx.x & 63;
    const float* in = tensor ? in2 : in1;
    unsigned short* outb = tensor ? in2b : in1b;
    const float* uA = u + (tensor ? 256 : 0);
    const float* uB = u + (tensor ? 512 : 768);
    float* sA = s + (tensor ? 1 : 0) * 16384;
    float* sB = s + (tensor ? 2 : 3) * 16384;

    float4_ v = *(const float4_*)(in + row * 256 + lane * 4);
    float4_ ua = *(const float4_*)(uA + lane * 4);
    float4_ ub = *(const float4_*)(uB + lane * 4);
    ushort4_ ob;
    ob.x = f2bf(v.x); ob.y = f2bf(v.y); ob.z = f2bf(v.z); ob.w = f2bf(v.w);
    *(ushort4_*)(outb + row * 256 + lane * 4) = ob;
    float accA = v.x * ua.x + v.y * ua.y + v.z * ua.z + v.w * ua.w;
    float accB = v.x * ub.x + v.y * ub.y + v.z * ub.z + v.w * ub.w;
    for (int off = 32; off; off >>= 1) {
        accA += __shfl_xor(accA, off, 64);
        accB += __shfl_xor(accB, off, 64);
    }
    if (lane == 0) { sA[row] = accA; sB[row] = accB; }
}

// ---------------------------------------------------------------------------
// Kernel 4: WhT = (W^T) @ (in^T) as bf16 MFMA GEMM.  (unchanged)
__global__ __launch_bounds__(256) void k_gemm_whT(const unsigned short* __restrict__ W1T,
                                                  const unsigned short* __restrict__ W2T,
                                                  const unsigned short* __restrict__ in1b,
                                                  const unsigned short* __restrict__ in2b,
                                                  unsigned short* __restrict__ whT1,
                                                  unsigned short* __restrict__ whT2) {
    __shared__ unsigned short sA[128 * 32];
    __shared__ unsigned short sB[128 * 32];
    int c = blockIdx.x >> 8;
    int bid = blockIdx.x & 255;
    int mt = bid & 1, ntile = bid >> 1;
    const unsigned short* A = c ? W2T : W1T;
    const unsigned short* Bm = c ? in1b : in2b;
    unsigned short* outp = c ? whT2 : whT1;
    int t = threadIdx.x;
    int w = t >> 6, lane = t & 63, l15 = lane & 15, lq = lane >> 4;
    int wm = (w & 1) * 64, wn = (w >> 1) * 64;
    f32x4 acc[4][4] = {};
    const unsigned short* gA = A + (mt * 128 + (t >> 2)) * 256 + (t & 3) * 8;
    const unsigned short* gB = Bm + (ntile * 128 + (t >> 2)) * 256 + (t & 3) * 8;

    for (int kk = 0; kk < 256; kk += 32) {
        lds_load16(gA + kk, &sA[t * 8]);
        lds_load16(gA + kk + 64 * 256, &sA[t * 8 + 2048]);
        lds_load16(gB + kk, &sB[t * 8]);
        lds_load16(gB + kk + 64 * 256, &sB[t * 8 + 2048]);
        __syncthreads();
        short8 af[4], bfr[4];
#pragma unroll
        for (int m2 = 0; m2 < 4; m2++) af[m2] = *(const short8*)&sA[(wm + m2 * 16 + l15) * 32 + lq * 8];
#pragma unroll
        for (int n2 = 0; n2 < 4; n2++) bfr[n2] = *(const short8*)&sB[(wn + n2 * 16 + l15) * 32 + lq * 8];
#pragma unroll
        for (int m2 = 0; m2 < 4; m2++)
#pragma unroll
            for (int n2 = 0; n2 < 4; n2++)
                acc[m2][n2] = __builtin_amdgcn_mfma_f32_16x16x32_bf16(af[m2], bfr[n2], acc[m2][n2], 0, 0, 0);
        __syncthreads();
    }
#pragma unroll
    for (int m2 = 0; m2 < 4; m2++) {
#pragma unroll
        for (int n2 = 0; n2 < 4; n2++) {
            int i_glob = ntile * 128 + wn + n2 * 16 + l15;
            int bb = i_glob >> 11, ii = i_glob & 2047;
#pragma unroll
            for (int r = 0; r < 4; r++) {
                int d = mt * 128 + wm + m2 * 16 + lq * 4 + r;
                outp[bb * (256 * 2048) + d * 2048 + ii] = f2bf(acc[m2][n2][r]);
            }
        }
    }
}

// ---------------------------------------------------------------------------
// Kernel 5: fused stats + probs + ctx = P @ V.
// grid 256 = 2a x 8b x 16mt (XCD-clustered), 512 threads (8 waves, 2M x 4N).
// Each block: 128 query rows x full 2048 keys x ALL 256 ctx columns.
__global__ __launch_bounds__(512) void k_attn(const float* __restrict__ s,
                                              const unsigned short* __restrict__ whT1,
                                              const unsigned short* __restrict__ whT2,
                                              const float* __restrict__ mask1, const float* __restrict__ mask2,
                                              float* __restrict__ out) {
    __shared__ unsigned short sP[128 * 40];  // stride 40 shorts (80B) breaks pow2 bank aliasing
    __shared__ unsigned short sV[256 * 32];
    __shared__ float lsk[2048];
    __shared__ float lmk[2048];
    __shared__ float lsq[128], lm[128], lil[128];

    // bijective XCD swizzle: blocks with the same (a,b) land on one XCD -> V panel L2-resident
    int lb = (blockIdx.x & 7) * 32 + (blockIdx.x >> 3);
    int a = lb >> 7, b = (lb >> 4) & 7, mt = lb & 15;
    int t = threadIdx.x;
    const float* skp = s + (a ? 3 : 1) * 16384 + b * 2048;
    const float* sqp = s + (a ? 2 : 0) * 16384 + b * 2048 + mt * 128;
    const float* mp = (a ? mask1 : mask2) + b * 2048;
    const unsigned short* V = (a ? whT2 : whT1) + b * (256 * 2048);
    float* pout = out + 8388608 + a * 33554432 + (b * 2048 + mt * 128) * 2048;
    float* cout = out + a * 4194304 + (b * 2048 + mt * 128) * 256;

    for (int j = t; j < 2048; j += 512) { lsk[j] = skp[j]; lmk[j] = mp[j]; }
    if (t < 128) lsq[t] = sqp[t];
    __syncthreads();

    int w = t >> 6, lane = t & 63, l15 = lane & 15, lq = lane >> 4;

    // fused softmax stats: wave w handles rows w*16 .. w*16+15 (all data LDS-resident)
    for (int rr = 0; rr < 16; rr++) {
        int row = w * 16 + rr;
        float sq = lsq[row];
        float mx = -3.4e38f;
        for (int j = lane; j < 2048; j += 64) {
            float x = sq + lsk[j];
            x = fmaxf(x, x * ALPHA) + lmk[j];
            mx = fmaxf(mx, x);
        }
        for (int off = 32; off; off >>= 1) mx = fmaxf(mx, __shfl_xor(mx, off, 64));
        float sum = 0.f;
        for (int j = lane; j < 2048; j += 64) {
            float x = sq + lsk[j];
            x = fmaxf(x, x * ALPHA) + lmk[j];
            sum += __expf(x - mx);
        }
        for (int off = 32; off; off >>= 1) sum += __shfl_xor(sum, off, 64);
        if (lane == 0) { lm[row] = mx; lil[row] = 1.0f / sum; }
    }
    __syncthreads();

    int wm = (w & 1) * 64, wn = (w >> 1) * 64;
    f32x4 acc[4][4] = {};
    int pi = t >> 2;          // P row this thread computes (4 threads/row)
    int pj = (t & 3) * 8;     // P col base (8 cols)
    const unsigned short* gV = V + (t >> 2) * 2048 + (t & 3) * 8;

    for (int j0 = 0; j0 < 2048; j0 += 32) {
        // async V tile [256 d][32 j]: two 16B issues per thread (rows t>>2 and t>>2+128)
        lds_load16(gV + j0, &sV[t * 8]);
        lds_load16(gV + j0 + 128 * 2048, &sV[t * 8 + 4096]);
        // pin the V loads above the probs stores so vmcnt(2) below is the stores, not the loads
        __builtin_amdgcn_sched_barrier(0);

        float sqv = lsq[pi], mv = lm[pi], ilv = lil[pi];
        float pv[8];
#pragma unroll
        for (int q = 0; q < 8; q++) {
            float x = sqv + lsk[j0 + pj + q];
            x = fmaxf(x, x * ALPHA) + lmk[j0 + pj + q];
            pv[q] = __expf(x - mv) * ilv;
        }
        // normalized probs, write-once -> nontemporal (keep V in L2)
        {
            float4_* gp = (float4_*)(pout + pi * 2048 + j0 + pj);
            float4_ v0, v1;
            v0.x = pv[0]; v0.y = pv[1]; v0.z = pv[2]; v0.w = pv[3];
            v1.x = pv[4]; v1.y = pv[5]; v1.z = pv[6]; v1.w = pv[7];
            __builtin_nontemporal_store(v0, gp);
            __builtin_nontemporal_store(v1, gp + 1);
        }
        union { short8 v; unsigned short u[8]; } pk;
#pragma unroll
        for (int q = 0; q < 8; q++) pk.u[q] = f2bf(pv[q]);
        *(short8*)&sP[pi * 40 + pj] = pk.v;

        // barrier 1: V tile landed (the 2 loads are the oldest VMEM ops), sP visible.
        // vmcnt(2) leaves THIS iteration's 2 probs stores in flight -> no store drain on critical path.
        asm volatile("s_waitcnt vmcnt(2) lgkmcnt(0)" ::: "memory");
        __builtin_amdgcn_s_barrier();

        short8 af[4], bfr[4];
#pragma unroll
        for (int m2 = 0; m2 < 4; m2++) af[m2] = *(const short8*)&sP[(wm + m2 * 16 + l15) * 40 + lq * 8];
#pragma unroll
        for (int n2 = 0; n2 < 4; n2++) bfr[n2] = *(const short8*)&sV[(wn + n2 * 16 + l15) * 32 + lq * 8];
#pragma unroll
        for (int m2 = 0; m2 < 4; m2++)
#pragma unroll
            for (int n2 = 0; n2 < 4; n2++)
                acc[m2][n2] = __builtin_amdgcn_mfma_f32_16x16x32_bf16(af[m2], bfr[n2], acc[m2][n2], 0, 0, 0);

        // barrier 2: LDS reads done before next iteration's staging overwrites sP/sV
        asm volatile("s_waitcnt lgkmcnt(0)" ::: "memory");
        __builtin_amdgcn_s_barrier();
    }

    // ctx epilogue: D[m=i][n=d], write-once -> nontemporal
#pragma unroll
    for (int m2 = 0; m2 < 4; m2++) {
#pragma unroll
        for (int n2 = 0; n2 < 4; n2++) {
#pragma unroll
            for (int r = 0; r < 4; r++) {
                int i_loc = wm + m2 * 16 + lq * 4 + r;
                int d_loc = wn + n2 * 16 + l15;
                __builtin_nontemporal_store(acc[m2][n2][r], cout + i_loc * 256 + d_loc);
            }
        }
    }
}

// ---------------------------------------------------------------------------
extern "C" void kernel_launch(void* const* d_in, const int* in_sizes, int n_in,
                              void* d_out, int out_size, void* d_ws, size_t ws_size,
                              hipStream_t stream) {
    const float* in1   = (const float*)d_in[0];
    const float* mask1 = (const float*)d_in[1];
    const float* in2   = (const float*)d_in[2];
    const float* mask2 = (const float*)d_in[3];
    const float* W1    = (const float*)d_in[4];
    const float* a1    = (const float*)d_in[5];
    const float* W2    = (const float*)d_in[6];
    const float* a2    = (const float*)d_in[7];
    float* out = (float*)d_out;
    char* ws = (char*)d_ws;

    unsigned short* in1b = (unsigned short*)(ws);
    unsigned short* in2b = (unsigned short*)(ws + 8388608);
    unsigned short* whT1 = (unsigned short*)(ws + 16777216);
    unsigned short* whT2 = (unsigned short*)(ws + 25165824);
    unsigned short* W1T  = (unsigned short*)(ws + 33554432);
    unsigned short* W2T  = (unsigned short*)(ws + 33685504);
    float* u    = (float*)(ws + 33816576);
    float* s    = (float*)(ws + 33820672);

    k_prep_w<<<512, 256, 0, stream>>>(W1, W2, W1T, W2T);
    k_prep_u<<<4, 256, 0, stream>>>(W1, a1, W2, a2, u);
    k_cast_s<<<8192, 256, 0, stream>>>(in1, in2, u, in1b, in2b, s);
    k_gemm_whT<<<512, 256, 0, stream>>>(W1T, W2T, in1b, in2b, whT1, whT2);
    k_attn<<<256, 512, 0, stream>>>(s, whT1, whT2, mask1, mask2, out);
}

// Round 2
// 404.874 us; speedup vs baseline: 1.2946x; 1.1407x over previous
//
#include <hip/hip_runtime.h>
#include <hip/hip_bf16.h>
#include <stdint.h>

#define ALPHA 0.01f

typedef __attribute__((ext_vector_type(8))) short short8;
typedef __attribute__((ext_vector_type(4))) float f32x4;
typedef __attribute__((ext_vector_type(4))) float float4_;
typedef __attribute__((ext_vector_type(4))) unsigned short ushort4_;
typedef unsigned int u32;

// round-to-nearest-even f32 -> bf16 bit pattern
static __device__ __forceinline__ unsigned short f2bf(float f) {
    union { float f; u32 u; } v; v.f = f;
    u32 r = v.u + 0x7FFF + ((v.u >> 16) & 1);
    return (unsigned short)(r >> 16);
}

// async global->LDS, 16B per lane. LDS dest is wave-uniform base + lane*16.
static __device__ __forceinline__ void lds_load16(const void* g, void* l) {
    __builtin_amdgcn_global_load_lds((const __attribute__((address_space(1))) u32*)g,
                                     (__attribute__((address_space(3))) u32*)l, 16, 0, 0);
}

// ---------------------------------------------------------------------------
// Kernel 1 (merged preps): blocks 0..511 cast W1/W2 to bf16 transposed;
// blocks 512..515 compute u[v][d] = sum_n W[d][n]*a_half[n]
__global__ __launch_bounds__(256) void k_prep(const float* __restrict__ W1, const float* __restrict__ a1,
                                              const float* __restrict__ W2, const float* __restrict__ a2,
                                              unsigned short* __restrict__ W1T, unsigned short* __restrict__ W2T,
                                              float* __restrict__ u) {
    int bb = blockIdx.x;
    if (bb < 512) {
        const float* W = (bb & 256) ? W2 : W1;
        unsigned short* WT = (bb & 256) ? W2T : W1T;
        int n = bb & 255, k = threadIdx.x;
        WT[n * 256 + k] = f2bf(W[k * 256 + n]);
    } else {
        int v = bb - 512;
        const float* W = (v < 2) ? W1 : W2;
        const float* a = ((v < 2) ? a1 : a2) + (v & 1) * 256;
        int d = threadIdx.x;
        float acc = 0.f;
        for (int n = 0; n < 256; n++) acc += W[d * 256 + n] * a[n];
        u[v * 256 + d] = acc;
    }
}

// Kernel 2: cast inputs to bf16 + compute the 4 score GEMVs in fp32.
__global__ __launch_bounds__(256) void k_cast_s(const float* __restrict__ in1, const float* __restrict__ in2,
                                                const float* __restrict__ u,
                                                unsigned short* __restrict__ in1b, unsigned short* __restrict__ in2b,
                                                float* __restrict__ s) {
    int gid = blockIdx.x * 4 + (threadIdx.x >> 6);   // one wave per row
    int tensor = gid >> 14;
    int row = gid & 16383;
    int lane = threadIdx.x & 63;
    const float* in = tensor ? in2 : in1;
    unsigned short* outb = tensor ? in2b : in1b;
    const float* uA = u + (tensor ? 256 : 0);
    const float* uB = u + (tensor ? 512 : 768);
    float* sA = s + (tensor ? 1 : 0) * 16384;
    float* sB = s + (tensor ? 2 : 3) * 16384;

    float4_ v = *(const float4_*)(in + row * 256 + lane * 4);
    float4_ ua = *(const float4_*)(uA + lane * 4);
    float4_ ub = *(const float4_*)(uB + lane * 4);
    ushort4_ ob;
    ob.x = f2bf(v.x); ob.y = f2bf(v.y); ob.z = f2bf(v.z); ob.w = f2bf(v.w);
    *(ushort4_*)(outb + row * 256 + lane * 4) = ob;
    float accA = v.x * ua.x + v.y * ua.y + v.z * ua.z + v.w * ua.w;
    float accB = v.x * ub.x + v.y * ub.y + v.z * ub.z + v.w * ub.w;
    for (int off = 32; off; off >>= 1) {
        accA += __shfl_xor(accA, off, 64);
        accB += __shfl_xor(accB, off, 64);
    }
    if (lane == 0) { sA[row] = accA; sB[row] = accB; }
}

// ---------------------------------------------------------------------------
// Kernel 3: WhT = (W^T) @ (in^T) as bf16 MFMA GEMM, double-buffered prefetch.
__global__ __launch_bounds__(256) void k_gemm_whT(const unsigned short* __restrict__ W1T,
                                                  const unsigned short* __restrict__ W2T,
                                                  const unsigned short* __restrict__ in1b,
                                                  const unsigned short* __restrict__ in2b,
                                                  unsigned short* __restrict__ whT1,
                                                  unsigned short* __restrict__ whT2) {
    __shared__ __attribute__((aligned(16))) unsigned short sA[2][128 * 32];
    __shared__ __attribute__((aligned(16))) unsigned short sB[2][128 * 32];
    int c = blockIdx.x >> 8;
    int bid = blockIdx.x & 255;
    int mt = bid & 1, ntile = bid >> 1;
    const unsigned short* A = c ? W2T : W1T;
    const unsigned short* Bm = c ? in1b : in2b;
    unsigned short* outp = c ? whT2 : whT1;
    int t = threadIdx.x;
    int w = t >> 6, lane = t & 63, l15 = lane & 15, lq = lane >> 4;
    int wm = (w & 1) * 64, wn = (w >> 1) * 64;
    f32x4 acc[4][4] = {};
    const unsigned short* gA = A + (mt * 128 + (t >> 2)) * 256 + (t & 3) * 8;
    const unsigned short* gB = Bm + (ntile * 128 + (t >> 2)) * 256 + (t & 3) * 8;

    // prologue: stage K-tile 0 into buf 0
    lds_load16(gA, &sA[0][t * 8]);
    lds_load16(gA + 64 * 256, &sA[0][t * 8 + 2048]);
    lds_load16(gB, &sB[0][t * 8]);
    lds_load16(gB + 64 * 256, &sB[0][t * 8 + 2048]);

    for (int it = 0; it < 8; ++it) {
        int kn = ((it + 1) & 7) * 32;             // wrap -> dummy re-stage on last iter
        unsigned short* dA = (unsigned short*)sA[(it + 1) & 1];
        unsigned short* dB = (unsigned short*)sB[(it + 1) & 1];
        lds_load16(gA + kn, dA + t * 8);
        lds_load16(gA + kn + 64 * 256, dA + t * 8 + 2048);
        lds_load16(gB + kn, dB + t * 8);
        lds_load16(gB + kn + 64 * 256, dB + t * 8 + 2048);
        __builtin_amdgcn_sched_barrier(0);
        // previous-iteration's 4 loads retired; this iteration's 4 stay in flight
        asm volatile("s_waitcnt vmcnt(4)" ::: "memory");
        __builtin_amdgcn_s_barrier();

        const unsigned short* cA = sA[it & 1];
        const unsigned short* cB = sB[it & 1];
        short8 af[4], bfr[4];
#pragma unroll
        for (int m2 = 0; m2 < 4; m2++) af[m2] = *(const short8*)&cA[(wm + m2 * 16 + l15) * 32 + lq * 8];
#pragma unroll
        for (int n2 = 0; n2 < 4; n2++) bfr[n2] = *(const short8*)&cB[(wn + n2 * 16 + l15) * 32 + lq * 8];
        __builtin_amdgcn_s_setprio(1);
#pragma unroll
        for (int m2 = 0; m2 < 4; m2++)
#pragma unroll
            for (int n2 = 0; n2 < 4; n2++)
                acc[m2][n2] = __builtin_amdgcn_mfma_f32_16x16x32_bf16(af[m2], bfr[n2], acc[m2][n2], 0, 0, 0);
        __builtin_amdgcn_s_setprio(0);
        asm volatile("s_waitcnt lgkmcnt(0)" ::: "memory");
        __builtin_amdgcn_s_barrier();
    }
#pragma unroll
    for (int m2 = 0; m2 < 4; m2++) {
#pragma unroll
        for (int n2 = 0; n2 < 4; n2++) {
            int i_glob = ntile * 128 + wn + n2 * 16 + l15;
            int bb = i_glob >> 11, ii = i_glob & 2047;
#pragma unroll
            for (int r = 0; r < 4; r++) {
                int d = mt * 128 + wm + m2 * 16 + lq * 4 + r;
                outp[bb * (256 * 2048) + d * 2048 + ii] = f2bf(acc[m2][n2][r]);
            }
        }
    }
}

// ---------------------------------------------------------------------------
// Kernel 4: fused stats + probs + ctx = P @ V.
// grid 512 = 2a x 8b x 32rg (XCD-clustered), 512 threads (8 waves 2Mx4N), 2 blocks/CU.
// Each block: 64 query rows x full 2048 keys x all 256 ctx cols.
// One-pass softmax stats via monotonicity: m = lrelu(sq + max_j sk) + max_j mk >= max_j x
// (exact when mask is constant; always a valid shift since softmax is shift-invariant).
__global__ __launch_bounds__(512, 4) void k_attn(const float* __restrict__ s,
                                                 const unsigned short* __restrict__ whT1,
                                                 const unsigned short* __restrict__ whT2,
                                                 const float* __restrict__ mask1, const float* __restrict__ mask2,
                                                 float* __restrict__ out) {
    __shared__ __attribute__((aligned(16))) unsigned short sP[64 * 40];   // stride 40 shorts
    __shared__ __attribute__((aligned(16))) unsigned short sV[2][256 * 32]; // double-buffered V tile
    __shared__ float lsk[2048];
    __shared__ float lmk[2048];
    __shared__ float lsq[64], lmx[64], lil[64];
    __shared__ float red[16];

    // bijective XCD swizzle: 64 consecutive lb per XCD = 2 full (a,b) panels -> V L2-resident
    int lb = (blockIdx.x & 7) * 64 + (blockIdx.x >> 3);
    int a = lb >> 8, b = (lb >> 5) & 7, rg = lb & 31;
    int t = threadIdx.x;
    const float* skp = s + (a ? 3 : 1) * 16384 + b * 2048;
    const float* sqp = s + (a ? 2 : 0) * 16384 + b * 2048 + rg * 64;
    const float* mp = (a ? mask1 : mask2) + b * 2048;
    const unsigned short* V = (a ? whT2 : whT1) + b * (256 * 2048);
    float* pout = out + 8388608 + a * 33554432 + (b * 2048 + rg * 64) * 2048;
    float* cout = out + a * 4194304 + (b * 2048 + rg * 64) * 256;

    // stage keys + mask, computing running maxes for the softmax shift
    float kmax = -3.4e38f, mmax = -3.4e38f;
    for (int j = t; j < 2048; j += 512) {
        float kv = skp[j], mv = mp[j];
        lsk[j] = kv; lmk[j] = mv;
        kmax = fmaxf(kmax, kv); mmax = fmaxf(mmax, mv);
    }
    if (t < 64) lsq[t] = sqp[t];
    int w = t >> 6, lane = t & 63;
    for (int off = 32; off; off >>= 1) {
        kmax = fmaxf(kmax, __shfl_xor(kmax, off, 64));
        mmax = fmaxf(mmax, __shfl_xor(mmax, off, 64));
    }
    if (lane == 0) { red[w] = kmax; red[8 + w] = mmax; }
    __syncthreads();
    float skmax = fmaxf(fmaxf(fmaxf(red[0], red[1]), fmaxf(red[2], red[3])),
                        fmaxf(fmaxf(red[4], red[5]), fmaxf(red[6], red[7])));
    float mkmax = fmaxf(fmaxf(fmaxf(red[8], red[9]), fmaxf(red[10], red[11])),
                        fmaxf(fmaxf(red[12], red[13]), fmaxf(red[14], red[15])));

    const float L2E = 1.44269504f;
    // single sum pass per row (max pass eliminated by the monotonic bound)
    for (int rr = 0; rr < 8; rr++) {
        int row = w * 8 + rr;
        float sq = lsq[row];
        float mb = sq + skmax; mb = fmaxf(mb, mb * ALPHA) + mkmax;
        float mL2 = mb * L2E;
        float sum = 0.f;
        for (int j = lane; j < 2048; j += 64) {
            float x = sq + lsk[j];
            x = fmaxf(x, x * ALPHA) + lmk[j];
            sum += exp2f(__builtin_fmaf(x, L2E, -mL2));
        }
        for (int off = 32; off; off >>= 1) sum += __shfl_xor(sum, off, 64);
        if (lane == 0) { lmx[row] = mL2; lil[row] = 1.0f / sum; }
    }
    __syncthreads();

    int l15 = lane & 15, lq = lane >> 4;
    int wr = w >> 2, wc = w & 3;            // 2M x 4N waves, wave tile 32x64
    f32x4 acc[2][4] = {};
    int pi = t >> 3, pj = (t & 7) * 4;      // this thread's P row / 4-col group
    const unsigned short* gV = V + (t >> 2) * 2048 + (t & 3) * 8;
    float sqv = lsq[pi];
    float mL2 = lmx[pi], ilv = lil[pi];     // loop-invariant, hoisted
    float* gp = pout + pi * 2048 + pj;
    const float* lskp = lsk + pj;
    const float* lmkp = lmk + pj;
    unsigned short* sPp = sP + pi * 40 + pj;

    // prologue: stage j-tile 0 into buf 0
    lds_load16(gV, &sV[0][t * 8]);
    lds_load16(gV + 128 * 2048, &sV[0][t * 8 + 4096]);

    for (int it = 0; it < 64; ++it) {
        int j0 = it * 32;
        int jn = (j0 + 32) & 2047;          // wrap -> dummy stage on last iter
        unsigned short* dst = (unsigned short*)sV[(it + 1) & 1];
        lds_load16(gV + jn, dst + t * 8);
        lds_load16(gV + jn + 128 * 2048, dst + t * 8 + 4096);
        __builtin_amdgcn_sched_barrier(0);  // keep loads above everything below

        float pv[4];
#pragma unroll
        for (int q = 0; q < 4; q++) {
            float x = sqv + lskp[j0 + q];
            x = fmaxf(x, x * ALPHA) + lmkp[j0 + q];
            pv[q] = exp2f(__builtin_fmaf(x, L2E, -mL2)) * ilv;
        }
        float4_ v0; v0.x = pv[0]; v0.y = pv[1]; v0.z = pv[2]; v0.w = pv[3];
        __builtin_nontemporal_store(v0, (float4_*)(gp + j0));
        union { unsigned long long u64; unsigned short us[4]; } pk;
        pk.us[0] = f2bf(pv[0]); pk.us[1] = f2bf(pv[1]); pk.us[2] = f2bf(pv[2]); pk.us[3] = f2bf(pv[3]);
        *(unsigned long long*)sPp = pk.u64;

        // wait: PREVIOUS iteration's V loads retired (latency hidden under this compute);
        // this iteration's 2 loads + 1 store stay in flight. lgkm: sP write visible.
        asm volatile("s_waitcnt vmcnt(3) lgkmcnt(0)" ::: "memory");
        __builtin_amdgcn_s_barrier();

        const unsigned short* sVc = sV[it & 1];
        short8 af[2], bfr[4];
#pragma unroll
        for (int m2 = 0; m2 < 2; m2++) af[m2] = *(const short8*)&sP[(wr * 32 + m2 * 16 + l15) * 40 + lq * 8];
#pragma unroll
        for (int n2 = 0; n2 < 4; n2++) bfr[n2] = *(const short8*)&sVc[(wc * 64 + n2 * 16 + l15) * 32 + lq * 8];
        __builtin_amdgcn_s_setprio(1);
#pragma unroll
        for (int m2 = 0; m2 < 2; m2++)
#pragma unroll
            for (int n2 = 0; n2 < 4; n2++)
                acc[m2][n2] = __builtin_amdgcn_mfma_f32_16x16x32_bf16(af[m2], bfr[n2], acc[m2][n2], 0, 0, 0);
        __builtin_amdgcn_s_setprio(0);
        // LDS reads done before next iteration overwrites sP
        asm volatile("s_waitcnt lgkmcnt(0)" ::: "memory");
        __builtin_amdgcn_s_barrier();
    }

    // ctx epilogue: D[m=i][n=d], write-once -> nontemporal
#pragma unroll
    for (int m2 = 0; m2 < 2; m2++) {
#pragma unroll
        for (int n2 = 0; n2 < 4; n2++) {
#pragma unroll
            for (int r = 0; r < 4; r++) {
                int i_loc = wr * 32 + m2 * 16 + lq * 4 + r;
                int d_loc = wc * 64 + n2 * 16 + l15;
                __builtin_nontemporal_store(acc[m2][n2][r], cout + i_loc * 256 + d_loc);
            }
        }
    }
}

// ---------------------------------------------------------------------------
extern "C" void kernel_launch(void* const* d_in, const int* in_sizes, int n_in,
                              void* d_out, int out_size, void* d_ws, size_t ws_size,
                              hipStream_t stream) {
    const float* in1   = (const float*)d_in[0];
    const float* mask1 = (const float*)d_in[1];
    const float* in2   = (const float*)d_in[2];
    const float* mask2 = (const float*)d_in[3];
    const float* W1    = (const float*)d_in[4];
    const float* a1    = (const float*)d_in[5];
    const float* W2    = (const float*)d_in[6];
    const float* a2    = (const float*)d_in[7];
    float* out = (float*)d_out;
    char* ws = (char*)d_ws;

    unsigned short* in1b = (unsigned short*)(ws);
    unsigned short* in2b = (unsigned short*)(ws + 8388608);
    unsigned short* whT1 = (unsigned short*)(ws + 16777216);
    unsigned short* whT2 = (unsigned short*)(ws + 25165824);
    unsigned short* W1T  = (unsigned short*)(ws + 33554432);
    unsigned short* W2T  = (unsigned short*)(ws + 33685504);
    float* u    = (float*)(ws + 33816576);
    float* s    = (float*)(ws + 33820672);

    k_prep<<<516, 256, 0, stream>>>(W1, a1, W2, a2, W1T, W2T, u);
    k_cast_s<<<8192, 256, 0, stream>>>(in1, in2, u, in1b, in2b, s);
    k_gemm_whT<<<512, 256, 0, stream>>>(W1T, W2T, in1b, in2b, whT1, whT2);
    k_attn<<<512, 512, 0, stream>>>(s, whT1, whT2, mask1, mask2, out);
}